// Round 8
// baseline (351.018 us; speedup 1.0000x reference)
//
#include <hip/hip_runtime.h>
#include <hip/hip_bf16.h>
#include <math.h>

#define CDIM 64
#define BATCH 2
#define KSPLIT 8
#define TK 64
#define M_FIX 44.0f        // fixed softmax max, log2 units (log2e folded into K)
#define LOG2E 1.44269504f

typedef __bf16 bf16x8 __attribute__((ext_vector_type(8)));
typedef __bf16 bf16x4 __attribute__((ext_vector_type(4)));
typedef __bf16 bf16x2 __attribute__((ext_vector_type(2)));
typedef float f32x4 __attribute__((ext_vector_type(4)));
typedef float f32x16 __attribute__((ext_vector_type(16)));

// ---------------------------------------------------------------------------
// Stage 1: fused 1x1-conv projections via MFMA, hi/lo bf16 split.
//   Q[n][c] (bf16), K[n][c] (bf16, scaled by log2e), V[c][n] (bf16, BN folded)
// grid (N/64, 3, B), block 256 (4 waves x 16 n).  [unchanged — known good]
// ---------------------------------------------------------------------------
__global__ __launch_bounds__(256) void gfa_stage1(
    const float* __restrict__ feature,
    const float* __restrict__ wa, const float* __restrict__ ba,
    const float* __restrict__ wb, const float* __restrict__ bb,
    const float* __restrict__ wm, const float* __restrict__ bm,
    const float* __restrict__ gma, const float* __restrict__ bta,
    const float* __restrict__ mean, const float* __restrict__ var,
    __bf16* __restrict__ Q, __bf16* __restrict__ K, __bf16* __restrict__ V,
    int N)
{
    const int tid  = threadIdx.x;
    const int w    = tid >> 6;
    const int lane = tid & 63;
    const int l15  = lane & 15;
    const int quad = lane >> 4;
    const int n0    = blockIdx.x * 64;
    const int which = blockIdx.y;
    const int b     = blockIdx.z;

    __shared__ __align__(16) char s1lds[35328];
    float*  Xs  = (float*)s1lds;              // [64][66] fp32
    __bf16* Whi = (__bf16*)(s1lds + 16896);   // [64][72]
    __bf16* Wlo = (__bf16*)(s1lds + 26112);   // [64][72]
    __bf16* Ts  = (__bf16*)s1lds;             // epilogue transpose (aliases Xs)

    const float* wsel = (which == 0) ? wa : (which == 1) ? wb : wm;
    const float* bsel = (which == 0) ? ba : (which == 1) ? bb : bm;
    const float wscale = (which == 1) ? LOG2E : 1.0f;   // fold log2e into K

    const float* fb = feature + (size_t)b * CDIM * N;
#pragma unroll
    for (int p = 0; p < 4; p++) {
        int idx = p * 256 + tid;
        int c = idx >> 4, n4 = (idx & 15) << 2;
        float4 v = *(const float4*)&fb[(size_t)c * N + n0 + n4];
        *(float2*)&Xs[c * 66 + n4]     = make_float2(v.x, v.y);
        *(float2*)&Xs[c * 66 + n4 + 2] = make_float2(v.z, v.w);
    }
#pragma unroll
    for (int p = 0; p < 4; p++) {
        int idx = p * 256 + tid;
        int o = idx >> 4, c4 = (idx & 15) << 2;
        float4 v = *(const float4*)&wsel[o * 64 + c4];
        bf16x4 hi, lo;
        float vv[4] = {v.x * wscale, v.y * wscale, v.z * wscale, v.w * wscale};
#pragma unroll
        for (int r = 0; r < 4; r++) {
            hi[r] = (__bf16)vv[r];
            lo[r] = (__bf16)(vv[r] - (float)hi[r]);
        }
        *(bf16x4*)&Whi[o * 72 + c4] = hi;
        *(bf16x4*)&Wlo[o * 72 + c4] = lo;
    }
    __syncthreads();

    const int nb = w * 16;
    bf16x8 xh[2], xl[2];
#pragma unroll
    for (int kc = 0; kc < 2; kc++) {
#pragma unroll
        for (int j = 0; j < 8; j++) {
            float xv = Xs[(kc * 32 + quad * 8 + j) * 66 + nb + l15];
            __bf16 h = (__bf16)xv;
            xh[kc][j] = h;
            xl[kc][j] = (__bf16)(xv - (float)h);
        }
    }

    f32x4 acc[4];
#pragma unroll
    for (int ot = 0; ot < 4; ot++) acc[ot] = (f32x4){0.f, 0.f, 0.f, 0.f};

#pragma unroll
    for (int ot = 0; ot < 4; ot++) {
#pragma unroll
        for (int kc = 0; kc < 2; kc++) {
            bf16x8 wh = *(const bf16x8*)&Whi[(ot * 16 + l15) * 72 + kc * 32 + quad * 8];
            bf16x8 wl = *(const bf16x8*)&Wlo[(ot * 16 + l15) * 72 + kc * 32 + quad * 8];
            acc[ot] = __builtin_amdgcn_mfma_f32_16x16x32_bf16(wh, xh[kc], acc[ot], 0, 0, 0);
            acc[ot] = __builtin_amdgcn_mfma_f32_16x16x32_bf16(wl, xh[kc], acc[ot], 0, 0, 0);
            acc[ot] = __builtin_amdgcn_mfma_f32_16x16x32_bf16(wh, xl[kc], acc[ot], 0, 0, 0);
        }
    }

    __syncthreads();
    if (which < 2) {
        __bf16* O = (which == 0 ? Q : K) + (size_t)b * N * CDIM;
#pragma unroll
        for (int ot = 0; ot < 4; ot++) {
            int o0 = ot * 16 + quad * 4;
            float4 b4 = *(const float4*)&bsel[o0];
            float bv[4] = {b4.x * wscale, b4.y * wscale, b4.z * wscale, b4.w * wscale};
            bf16x4 pk;
#pragma unroll
            for (int r = 0; r < 4; r++) pk[r] = (__bf16)(acc[ot][r] + bv[r]);
            *(bf16x4*)&Ts[(nb + l15) * 68 + o0] = pk;
        }
        __syncthreads();
#pragma unroll
        for (int p = 0; p < 2; p++) {
            int idx = p * 256 + tid;
            int row = idx >> 3, c8 = (idx & 7) * 8;
            *(int4*)&O[(size_t)(n0 + row) * CDIM + c8] = *(int4*)&Ts[row * 68 + c8];
        }
    } else {
        __bf16* Vb = V + (size_t)b * CDIM * N;
#pragma unroll
        for (int ot = 0; ot < 4; ot++) {
            int o0 = ot * 16 + quad * 4;
            float4 b4 = *(const float4*)&bsel[o0];
            float4 m4 = *(const float4*)&mean[o0];
            float4 v4 = *(const float4*)&var[o0];
            float4 g4 = *(const float4*)&gma[o0];
            float4 t4 = *(const float4*)&bta[o0];
            float bv[4] = {b4.x, b4.y, b4.z, b4.w};
            float mv[4] = {m4.x, m4.y, m4.z, m4.w};
            float vv[4] = {v4.x, v4.y, v4.z, v4.w};
            float gv[4] = {g4.x, g4.y, g4.z, g4.w};
            float tv[4] = {t4.x, t4.y, t4.z, t4.w};
#pragma unroll
            for (int r = 0; r < 4; r++) {
                float s = gv[r] * rsqrtf(vv[r] + 1e-5f);
                float val = (acc[ot][r] + bv[r] - mv[r]) * s + tv[r];
                Ts[(o0 + r) * 68 + nb + l15] = (__bf16)val;
            }
        }
        __syncthreads();
#pragma unroll
        for (int p = 0; p < 2; p++) {
            int idx = p * 256 + tid;
            int row = idx >> 3, n8 = (idx & 7) * 8;
            *(int4*)&Vb[(size_t)row * N + n0 + n8] = *(int4*)&Ts[row * 68 + n8];
        }
    }
}

// ---------------------------------------------------------------------------
// Stage 2: flash attention, kv-split, fixed-max softmax, 32x32x16 MFMA.
//  - 32 q/wave (128 q/block): acc 32 + qf 16 regs -> fits 3 blocks/CU
//    budget (512/3 ~ 170 unified) WITHOUT spilling (R7's failure mode).
//  - P never touches LDS: QK C-layout -> PV B-layout via 8 dword
//    __shfl_xor(,32) half-exchanges + cndmask selects per 32-kv chunk.
//  - K/V tiles stride 136 B (2 mod 32 dw): frag reads 2-way = free (R7: 0 conflicts).
//  - LDS 17408 B; grid (N/128, KSPLIT, B) = 1024 blocks, 3/CU resident.
//  - fused atomic-ticket reduction tail (validated R7).
// ---------------------------------------------------------------------------
__global__ __launch_bounds__(256, 3) void gfa_stage2(
    const __bf16* __restrict__ Q, const __bf16* __restrict__ K,
    const __bf16* __restrict__ V,
    __bf16* __restrict__ Upart, float* __restrict__ stats,
    int* __restrict__ counters,
    const float* __restrict__ feature, const float* __restrict__ alpha_p,
    float* __restrict__ out, int N)
{
    const int tid  = threadIdx.x;
    const int w    = tid >> 6;
    const int lane = tid & 63;
    const int l31  = lane & 31;
    const int half = lane >> 5;
    const int qt_  = blockIdx.x;
    const int sp   = blockIdx.y;
    const int b    = blockIdx.z;
    const int qb   = qt_ * 128 + w * 32;   // wave's 32-q base
    const int QT   = N >> 6;               // 64-q tiles
    const int QT128 = N >> 7;              // 128-q tiles

    __shared__ __align__(16) char lds[17408];
    __shared__ int is_last;
    char* Kt = lds;                        // [64 kv][136B]  K[kv][c]
    char* Vt = lds + 8704;                 // [64 c ][136B]  V[c][kv]

    const __bf16* Qg = Q + (size_t)b * N * CDIM;
    const __bf16* Kg = K + (size_t)b * N * CDIM;
    const __bf16* Vg = V + (size_t)b * CDIM * N;
    const int kvb = sp * (N / KSPLIT);
    const int r8 = tid >> 3, c16 = (tid & 7) * 16;

    // Q B-fragments (loop-invariant): q = qb + l31, k-chunk kc*16 + half*8
    bf16x8 qf[4];
#pragma unroll
    for (int kc = 0; kc < 4; kc++)
        qf[kc] = *(const bf16x8*)((const char*)Qg
            + (size_t)(qb + l31) * 128 + kc * 32 + half * 16);

    f32x16 acc[2];   // [ct]: out^T rows c = ct*32 + (r&3)+8*(r>>2)+4*half, col q
#pragma unroll
    for (int ct = 0; ct < 2; ct++)
#pragma unroll
        for (int r = 0; r < 16; r++) acc[ct][r] = 0.f;
    float l_run = 0.f;

    const int NIT = N / KSPLIT / TK;
    for (int it = 0; it < NIT; it++) {
        const int kv0 = kvb + it * TK;
        __syncthreads();
#pragma unroll
        for (int p = 0; p < 2; p++) {   // K tile: 64 x 128B
            int r = p * 32 + r8;
            *(int4*)(Kt + r * 136 + c16) =
                *(const int4*)((const char*)Kg + (size_t)(kv0 + r) * 128 + c16);
        }
#pragma unroll
        for (int p = 0; p < 2; p++) {   // V tile: 64 x 128B
            int r = p * 32 + r8;
            *(int4*)(Vt + r * 136 + c16) =
                *(const int4*)((const char*)Vg + ((size_t)r * N + kv0) * 2 + c16);
        }
        __syncthreads();

#pragma unroll
        for (int kvt = 0; kvt < 2; kvt++) {
            // QK^T: S^T[kv][q] for this 32-kv chunk
            f32x16 s16;
#pragma unroll
            for (int r = 0; r < 16; r++) s16[r] = 0.f;
#pragma unroll
            for (int kc = 0; kc < 4; kc++) {
                bf16x8 kf = *(const bf16x8*)(Kt + (kvt * 32 + l31) * 136 + kc * 32 + half * 16);
                s16 = __builtin_amdgcn_mfma_f32_32x32x16_bf16(kf, qf[kc], s16, 0, 0, 0);
            }
            // softmax (fixed max, log2 domain) -> packed bf16 pairs in regs
            // lane holds kv_r = (r&3)+8*(r>>2)+4*half; pk[d] packs (p[2d],p[2d+1])
            unsigned pk[8];
            float s = 0.f;
#pragma unroll
            for (int d = 0; d < 8; d++) {
                float p0 = __builtin_amdgcn_exp2f(s16[2 * d]     - M_FIX);
                float p1 = __builtin_amdgcn_exp2f(s16[2 * d + 1] - M_FIX);
                s += p0 + p1;
                union { bf16x2 h; unsigned u; } cv;
                cv.h[0] = (__bf16)p0; cv.h[1] = (__bf16)p1;
                pk[d] = cv.u;
            }
            l_run += s;
            // half-exchange: partner (lane^32) holds the other 16 kv rows
            unsigned xk[8];
#pragma unroll
            for (int d = 0; d < 8; d++)
                xk[d] = (unsigned)__shfl_xor((int)pk[d], 32);
            // PV B-frags: frag(ks=0) from pk0..3/xk0..3, frag(ks=1) from pk4..7/xk4..7
#pragma unroll
            for (int ks = 0; ks < 2; ks++) {
                union { unsigned u[4]; bf16x8 v; } pf;
                const int d0 = ks * 4;
                pf.u[0] = half ? xk[d0 + 2] : pk[d0 + 0];
                pf.u[1] = half ? xk[d0 + 3] : pk[d0 + 1];
                pf.u[2] = half ? pk[d0 + 2] : xk[d0 + 0];
                pf.u[3] = half ? pk[d0 + 3] : xk[d0 + 1];
#pragma unroll
                for (int ct = 0; ct < 2; ct++) {
                    bf16x8 vf = *(const bf16x8*)(Vt + (ct * 32 + l31) * 136
                                                 + kvt * 64 + ks * 32 + half * 16);
                    acc[ct] = __builtin_amdgcn_mfma_f32_32x32x16_bf16(vf, pf.v, acc[ct], 0, 0, 0);
                }
            }
        }
    }

    // write partials: per-wave 32-q slice of a 64-q tile -> Upart (bf16) + stats
    const int qt64 = qt_ * 2 + (w >> 1);
    const int qq = (w & 1) * 32 + l31;
    __bf16* Ub = Upart + ((size_t)(b * KSPLIT + sp) * QT + qt64) * 4096;
    float*  Sb = stats + ((size_t)(b * KSPLIT + sp) * QT + qt64) * 64;
    {
        float s = l_run + __shfl_xor(l_run, 32);
#pragma unroll
        for (int ct = 0; ct < 2; ct++)
#pragma unroll
            for (int r = 0; r < 16; r++) {
                int c = ct * 32 + (r & 3) + 8 * (r >> 2) + 4 * half;
                Ub[c * 64 + qq] = (__bf16)acc[ct][r];
            }
        if (half == 0) Sb[qq] = s;
    }

    // ---- fused flash-decode reduction tail ----
    __threadfence();                       // release Ub/Sb
    if (tid == 0) {
        int old = atomicAdd(&counters[b * QT128 + qt_], 1);
        is_last = (old == KSPLIT - 1);
    }
    __syncthreads();
    if (!is_last) return;
    __threadfence();                       // acquire all splits' Ub/Sb

    const int qr = tid & 63;
    const int cg = tid >> 6;               // 4 groups of 16 c
    const float a2 = 2.f * alpha_p[0];
#pragma unroll
    for (int t4 = 0; t4 < 2; t4++) {
        const int qt64r = qt_ * 2 + t4;
        float L = 0.f;
#pragma unroll
        for (int s = 0; s < KSPLIT; s++)
            L += stats[((size_t)(b * KSPLIT + s) * QT + qt64r) * 64 + qr];
        const float scale = a2 / L;
        const int n = qt64r * 64 + qr;
#pragma unroll
        for (int i = 0; i < 16; i++) {
            const int c = cg * 16 + i;
            float u = 0.f;
#pragma unroll
            for (int s = 0; s < KSPLIT; s++)
                u += (float)Upart[((size_t)(b * KSPLIT + s) * QT + qt64r) * 4096 + c * 64 + qr];
            const size_t gi = ((size_t)b * CDIM + c) * N + n;
            out[gi] = 2.f * feature[gi] + scale * u;
        }
    }
}

// ---------------------------------------------------------------------------
extern "C" void kernel_launch(void* const* d_in, const int* in_sizes, int n_in,
                              void* d_out, int out_size, void* d_ws, size_t ws_size,
                              hipStream_t stream) {
    const float* feature = (const float*)d_in[0];
    const float* wa   = (const float*)d_in[1];
    const float* ba   = (const float*)d_in[2];
    const float* wb   = (const float*)d_in[3];
    const float* bb   = (const float*)d_in[4];
    const float* wm   = (const float*)d_in[5];
    const float* bm   = (const float*)d_in[6];
    const float* gma  = (const float*)d_in[7];
    const float* bta  = (const float*)d_in[8];
    const float* mean = (const float*)d_in[9];
    const float* var  = (const float*)d_in[10];
    const float* alpha = (const float*)d_in[11];
    const int N = in_sizes[0] / (BATCH * CDIM);   // 8192

    __bf16* Q = (__bf16*)d_ws;
    __bf16* K = Q + (size_t)BATCH * N * CDIM;
    __bf16* V = K + (size_t)BATCH * N * CDIM;
    __bf16* Upart = V + (size_t)BATCH * N * CDIM;
    float* stats = (float*)(Upart + (size_t)BATCH * KSPLIT * (N / 64) * 4096);
    int* counters = (int*)(stats + (size_t)BATCH * KSPLIT * (N / 64) * 64);

    hipMemsetAsync(counters, 0, BATCH * (N / 128) * sizeof(int), stream);

    dim3 g1(N / 64, 3, BATCH);
    gfa_stage1<<<g1, 256, 0, stream>>>(feature, wa, ba, wb, bb, wm, bm,
                                       gma, bta, mean, var, Q, K, V, N);
    dim3 g2(N / 128, KSPLIT, BATCH);
    gfa_stage2<<<g2, 256, 0, stream>>>(Q, K, V, Upart, stats, counters,
                                       feature, alpha, (float*)d_out, N);
}

// Round 9
// 151.351 us; speedup vs baseline: 2.3192x; 2.3192x over previous
//
#include <hip/hip_runtime.h>
#include <hip/hip_bf16.h>
#include <math.h>

#define CDIM 64
#define BATCH 2
#define KSPLIT 8
#define TK 64
#define M_FIX 44.0f        // fixed softmax max, log2 units (log2e folded into K)
#define LOG2E 1.44269504f

typedef __bf16 bf16x8 __attribute__((ext_vector_type(8)));
typedef __bf16 bf16x4 __attribute__((ext_vector_type(4)));
typedef float f32x4 __attribute__((ext_vector_type(4)));
typedef float f32x16 __attribute__((ext_vector_type(16)));

// ---------------------------------------------------------------------------
// Stage 1: fused 1x1-conv projections via MFMA, hi/lo bf16 split.
//   Q[n][c] (bf16), K[n][c] (bf16, scaled by log2e), V[c][n] (bf16, BN folded)
// grid (N/64, 3, B), block 256 (4 waves x 16 n).  [unchanged — known good]
// ---------------------------------------------------------------------------
__global__ __launch_bounds__(256) void gfa_stage1(
    const float* __restrict__ feature,
    const float* __restrict__ wa, const float* __restrict__ ba,
    const float* __restrict__ wb, const float* __restrict__ bb,
    const float* __restrict__ wm, const float* __restrict__ bm,
    const float* __restrict__ gma, const float* __restrict__ bta,
    const float* __restrict__ mean, const float* __restrict__ var,
    __bf16* __restrict__ Q, __bf16* __restrict__ K, __bf16* __restrict__ V,
    int N)
{
    const int tid  = threadIdx.x;
    const int w    = tid >> 6;
    const int lane = tid & 63;
    const int l15  = lane & 15;
    const int quad = lane >> 4;
    const int n0    = blockIdx.x * 64;
    const int which = blockIdx.y;
    const int b     = blockIdx.z;

    __shared__ __align__(16) char s1lds[35328];
    float*  Xs  = (float*)s1lds;              // [64][66] fp32
    __bf16* Whi = (__bf16*)(s1lds + 16896);   // [64][72]
    __bf16* Wlo = (__bf16*)(s1lds + 26112);   // [64][72]
    __bf16* Ts  = (__bf16*)s1lds;             // epilogue transpose (aliases Xs)

    const float* wsel = (which == 0) ? wa : (which == 1) ? wb : wm;
    const float* bsel = (which == 0) ? ba : (which == 1) ? bb : bm;
    const float wscale = (which == 1) ? LOG2E : 1.0f;   // fold log2e into K

    const float* fb = feature + (size_t)b * CDIM * N;
#pragma unroll
    for (int p = 0; p < 4; p++) {
        int idx = p * 256 + tid;
        int c = idx >> 4, n4 = (idx & 15) << 2;
        float4 v = *(const float4*)&fb[(size_t)c * N + n0 + n4];
        *(float2*)&Xs[c * 66 + n4]     = make_float2(v.x, v.y);
        *(float2*)&Xs[c * 66 + n4 + 2] = make_float2(v.z, v.w);
    }
#pragma unroll
    for (int p = 0; p < 4; p++) {
        int idx = p * 256 + tid;
        int o = idx >> 4, c4 = (idx & 15) << 2;
        float4 v = *(const float4*)&wsel[o * 64 + c4];
        bf16x4 hi, lo;
        float vv[4] = {v.x * wscale, v.y * wscale, v.z * wscale, v.w * wscale};
#pragma unroll
        for (int r = 0; r < 4; r++) {
            hi[r] = (__bf16)vv[r];
            lo[r] = (__bf16)(vv[r] - (float)hi[r]);
        }
        *(bf16x4*)&Whi[o * 72 + c4] = hi;
        *(bf16x4*)&Wlo[o * 72 + c4] = lo;
    }
    __syncthreads();

    const int nb = w * 16;
    bf16x8 xh[2], xl[2];
#pragma unroll
    for (int kc = 0; kc < 2; kc++) {
#pragma unroll
        for (int j = 0; j < 8; j++) {
            float xv = Xs[(kc * 32 + quad * 8 + j) * 66 + nb + l15];
            __bf16 h = (__bf16)xv;
            xh[kc][j] = h;
            xl[kc][j] = (__bf16)(xv - (float)h);
        }
    }

    f32x4 acc[4];
#pragma unroll
    for (int ot = 0; ot < 4; ot++) acc[ot] = (f32x4){0.f, 0.f, 0.f, 0.f};

#pragma unroll
    for (int ot = 0; ot < 4; ot++) {
#pragma unroll
        for (int kc = 0; kc < 2; kc++) {
            bf16x8 wh = *(const bf16x8*)&Whi[(ot * 16 + l15) * 72 + kc * 32 + quad * 8];
            bf16x8 wl = *(const bf16x8*)&Wlo[(ot * 16 + l15) * 72 + kc * 32 + quad * 8];
            acc[ot] = __builtin_amdgcn_mfma_f32_16x16x32_bf16(wh, xh[kc], acc[ot], 0, 0, 0);
            acc[ot] = __builtin_amdgcn_mfma_f32_16x16x32_bf16(wl, xh[kc], acc[ot], 0, 0, 0);
            acc[ot] = __builtin_amdgcn_mfma_f32_16x16x32_bf16(wh, xl[kc], acc[ot], 0, 0, 0);
        }
    }

    __syncthreads();
    if (which < 2) {
        __bf16* O = (which == 0 ? Q : K) + (size_t)b * N * CDIM;
#pragma unroll
        for (int ot = 0; ot < 4; ot++) {
            int o0 = ot * 16 + quad * 4;
            float4 b4 = *(const float4*)&bsel[o0];
            float bv[4] = {b4.x * wscale, b4.y * wscale, b4.z * wscale, b4.w * wscale};
            bf16x4 pk;
#pragma unroll
            for (int r = 0; r < 4; r++) pk[r] = (__bf16)(acc[ot][r] + bv[r]);
            *(bf16x4*)&Ts[(nb + l15) * 68 + o0] = pk;
        }
        __syncthreads();
#pragma unroll
        for (int p = 0; p < 2; p++) {
            int idx = p * 256 + tid;
            int row = idx >> 3, c8 = (idx & 7) * 8;
            *(int4*)&O[(size_t)(n0 + row) * CDIM + c8] = *(int4*)&Ts[row * 68 + c8];
        }
    } else {
        __bf16* Vb = V + (size_t)b * CDIM * N;
#pragma unroll
        for (int ot = 0; ot < 4; ot++) {
            int o0 = ot * 16 + quad * 4;
            float4 b4 = *(const float4*)&bsel[o0];
            float4 m4 = *(const float4*)&mean[o0];
            float4 v4 = *(const float4*)&var[o0];
            float4 g4 = *(const float4*)&gma[o0];
            float4 t4 = *(const float4*)&bta[o0];
            float bv[4] = {b4.x, b4.y, b4.z, b4.w};
            float mv[4] = {m4.x, m4.y, m4.z, m4.w};
            float vv[4] = {v4.x, v4.y, v4.z, v4.w};
            float gv[4] = {g4.x, g4.y, g4.z, g4.w};
            float tv[4] = {t4.x, t4.y, t4.z, t4.w};
#pragma unroll
            for (int r = 0; r < 4; r++) {
                float s = gv[r] * rsqrtf(vv[r] + 1e-5f);
                float val = (acc[ot][r] + bv[r] - mv[r]) * s + tv[r];
                Ts[(o0 + r) * 68 + nb + l15] = (__bf16)val;
            }
        }
        __syncthreads();
#pragma unroll
        for (int p = 0; p < 2; p++) {
            int idx = p * 256 + tid;
            int row = idx >> 3, n8 = (idx & 7) * 8;
            *(int4*)&Vb[(size_t)row * N + n0 + n8] = *(int4*)&Ts[row * 68 + n8];
        }
    }
}

// ---------------------------------------------------------------------------
// Stage 2: flash attention, kv-split, fixed-max softmax, 32x32x16 MFMA.
// BARRIER-FREE K-loop: K and V A-operand fragments are loaded DIRECTLY from
// global (per-lane 16B reads; the 4 waves' repeated tile reads hit L1, so
// L2/HBM traffic is unchanged vs LDS staging). Only the per-wave-PRIVATE
// P strip lives in LDS ([64 q][136 B], conflict-free, no cross-wave
// sharing -> ZERO __syncthreads in the loop; no barrier drains).
// 64 q/wave (acc 64 + qf 32 regs) at launch_bounds(256,2): 256-reg budget.
// grid (N/256, KSPLIT, B) = 512 blocks, 2/CU resident.
// ---------------------------------------------------------------------------
__global__ __launch_bounds__(256, 2) void gfa_stage2(
    const __bf16* __restrict__ Q, const __bf16* __restrict__ K,
    const __bf16* __restrict__ V,
    __bf16* __restrict__ Upart, float* __restrict__ stats, int N)
{
    const int tid  = threadIdx.x;
    const int w    = tid >> 6;
    const int lane = tid & 63;
    const int l31  = lane & 31;
    const int half = lane >> 5;
    const int qt_  = blockIdx.x;
    const int sp   = blockIdx.y;
    const int b    = blockIdx.z;
    const int qb   = qt_ * 256 + w * 64;
    const int QT   = N >> 6;

    __shared__ __align__(16) char lds[34816];   // 4 waves x [64 q][136 B]
    char* Pw = lds + w * 8704;

    const __bf16* Qg = Q + (size_t)b * N * CDIM;
    const char*   Kg = (const char*)(K + (size_t)b * N * CDIM);
    const char*   Vg = (const char*)(V + (size_t)b * CDIM * N);
    const int kvb = sp * (N / KSPLIT);

    // Q B-fragments (loop-invariant)
    bf16x8 qf[2][4];
#pragma unroll
    for (int qt = 0; qt < 2; qt++)
#pragma unroll
        for (int kc = 0; kc < 4; kc++)
            qf[qt][kc] = *(const bf16x8*)((const char*)Qg
                + (size_t)(qb + qt * 32 + l31) * 128 + kc * 32 + half * 16);

    f32x16 acc[2][2];
#pragma unroll
    for (int qt = 0; qt < 2; qt++)
#pragma unroll
        for (int ct = 0; ct < 2; ct++)
#pragma unroll
            for (int r = 0; r < 16; r++) acc[qt][ct][r] = 0.f;
    float l_run[2] = {0.f, 0.f};

    const int NIT = N / KSPLIT / TK;
    for (int it = 0; it < NIT; it++) {
        const int kv0 = kvb + it * TK;

        // QK^T: S^T[kv][q]; kf direct from global (A-frag: lane=kv row, 16B of c)
#pragma unroll
        for (int kvt = 0; kvt < 2; kvt++) {
            bf16x8 kf[4];
#pragma unroll
            for (int kc = 0; kc < 4; kc++)
                kf[kc] = *(const bf16x8*)(Kg
                    + (size_t)(kv0 + kvt * 32 + l31) * 128 + kc * 32 + half * 16);
#pragma unroll
            for (int qt = 0; qt < 2; qt++) {
                f32x16 s16;
#pragma unroll
                for (int r = 0; r < 16; r++) s16[r] = 0.f;
#pragma unroll
                for (int kc = 0; kc < 4; kc++)
                    s16 = __builtin_amdgcn_mfma_f32_32x32x16_bf16(kf[kc], qf[qt][kc], s16, 0, 0, 0);
                float s = 0.f;
#pragma unroll
                for (int rg = 0; rg < 4; rg++) {
                    bf16x4 pb;
#pragma unroll
                    for (int r = 0; r < 4; r++) {
                        float p = __builtin_amdgcn_exp2f(s16[rg * 4 + r] - M_FIX);
                        s += p;
                        pb[r] = (__bf16)p;
                    }
                    *(bf16x4*)(Pw + (qt * 32 + l31) * 136
                               + (kvt * 32 + rg * 8 + half * 4) * 2) = pb;
                }
                l_run[qt] += s;
            }
        }

        // PV: out^T[c][q] += V[c][kv]·P^T[kv][q]; vf direct from global
        // (A-frag: lane=c row, 16B of kv), pf from the private P strip.
#pragma unroll
        for (int ks = 0; ks < 4; ks++) {
            bf16x8 vf[2], pf[2];
#pragma unroll
            for (int ct = 0; ct < 2; ct++)
                vf[ct] = *(const bf16x8*)(Vg
                    + ((size_t)(ct * 32 + l31) * N + kv0) * 2 + ks * 32 + half * 16);
#pragma unroll
            for (int qt = 0; qt < 2; qt++)
                pf[qt] = *(const bf16x8*)(Pw + (qt * 32 + l31) * 136 + ks * 32 + half * 16);
#pragma unroll
            for (int qt = 0; qt < 2; qt++)
#pragma unroll
                for (int ct = 0; ct < 2; ct++)
                    acc[qt][ct] = __builtin_amdgcn_mfma_f32_32x32x16_bf16(vf[ct], pf[qt], acc[qt][ct], 0, 0, 0);
        }
    }

    // epilogue: per-wave 64-q tile -> Upart (bf16) + stats
    const int qt64 = qt_ * 4 + w;
    __bf16* Ub = Upart + ((size_t)(b * KSPLIT + sp) * QT + qt64) * 4096;
    float*  Sb = stats + ((size_t)(b * KSPLIT + sp) * QT + qt64) * 64;
#pragma unroll
    for (int qt = 0; qt < 2; qt++) {
        float s = l_run[qt] + __shfl_xor(l_run[qt], 32);
        int qq = qt * 32 + l31;
#pragma unroll
        for (int ct = 0; ct < 2; ct++)
#pragma unroll
            for (int r = 0; r < 16; r++) {
                int c = ct * 32 + (r & 3) + 8 * (r >> 2) + 4 * half;
                Ub[c * 64 + qq] = (__bf16)acc[qt][ct][r];
            }
        if (half == 0) Sb[qq] = s;
    }
}

// ---------------------------------------------------------------------------
// Reduce: plain sum across KSPLIT + residual epilogue.  [R5 version]
// grid (N/64, 4, B), block 256: 64 q x 16 c per block; thread = 1 q x 4 c.
// ---------------------------------------------------------------------------
__global__ __launch_bounds__(256) void gfa_reduce(
    const float* __restrict__ feature, const float* __restrict__ alpha_p,
    const __bf16* __restrict__ Upart, const float* __restrict__ stats,
    float* __restrict__ out, int N)
{
    const int qt = blockIdx.x;
    const int cq = blockIdx.y;
    const int b  = blockIdx.z;
    const int q  = threadIdx.x & 63;
    const int c0 = cq * 16 + (threadIdx.x >> 6) * 4;
    const int QT = N >> 6;

    float L = 0.f;
#pragma unroll
    for (int s = 0; s < KSPLIT; s++)
        L += stats[((size_t)(b * KSPLIT + s) * QT + qt) * 64 + q];

    float u[4] = {0.f, 0.f, 0.f, 0.f};
#pragma unroll
    for (int s = 0; s < KSPLIT; s++) {
        const __bf16* Ub = Upart + ((size_t)(b * KSPLIT + s) * QT + qt) * 4096;
#pragma unroll
        for (int i = 0; i < 4; i++)
            u[i] += (float)Ub[(c0 + i) * 64 + q];
    }

    float scale = 2.f * alpha_p[0] / L;
    const int n = qt * 64 + q;
#pragma unroll
    for (int i = 0; i < 4; i++) {
        size_t gi = ((size_t)b * CDIM + c0 + i) * N + n;
        out[gi] = 2.f * feature[gi] + scale * u[i];
    }
}

// ---------------------------------------------------------------------------
extern "C" void kernel_launch(void* const* d_in, const int* in_sizes, int n_in,
                              void* d_out, int out_size, void* d_ws, size_t ws_size,
                              hipStream_t stream) {
    const float* feature = (const float*)d_in[0];
    const float* wa   = (const float*)d_in[1];
    const float* ba   = (const float*)d_in[2];
    const float* wb   = (const float*)d_in[3];
    const float* bb   = (const float*)d_in[4];
    const float* wm   = (const float*)d_in[5];
    const float* bm   = (const float*)d_in[6];
    const float* gma  = (const float*)d_in[7];
    const float* bta  = (const float*)d_in[8];
    const float* mean = (const float*)d_in[9];
    const float* var  = (const float*)d_in[10];
    const float* alpha = (const float*)d_in[11];
    const int N = in_sizes[0] / (BATCH * CDIM);   // 8192

    __bf16* Q = (__bf16*)d_ws;
    __bf16* K = Q + (size_t)BATCH * N * CDIM;
    __bf16* V = K + (size_t)BATCH * N * CDIM;
    __bf16* Upart = V + (size_t)BATCH * N * CDIM;
    float* stats = (float*)(Upart + (size_t)BATCH * KSPLIT * (N / 64) * 4096);

    dim3 g1(N / 64, 3, BATCH);
    gfa_stage1<<<g1, 256, 0, stream>>>(feature, wa, ba, wb, bb, wm, bm,
                                       gma, bta, mean, var, Q, K, V, N);
    dim3 g2(N / 256, KSPLIT, BATCH);
    gfa_stage2<<<g2, 256, 0, stream>>>(Q, K, V, Upart, stats, N);
    dim3 g3(N / 64, 4, BATCH);
    gfa_reduce<<<g3, 256, 0, stream>>>(feature, alpha, Upart, stats, (float*)d_out, N);
}